// Round 6
// baseline (218.322 us; speedup 1.0000x reference)
//
#include <hip/hip_runtime.h>
#include <math.h>

#define D_FEAT 128
#define SCAN_B 256
#define C_MAX  40
#define FIXP   33554432.0f   // 2^25 fixed-point scale for packed degree sum

#define FLAG_AGG (1ull << 32)
#define FLAG_INC (2ull << 32)

// ---------------- bf16 helpers ----------------

__device__ __forceinline__ unsigned bf16_rne(float x) {
    unsigned u = __float_as_uint(x);
    return (u + 0x7fffu + ((u >> 16) & 1u)) >> 16;
}
__device__ __forceinline__ unsigned pack2(float x, float y) {
    return bf16_rne(x) | (bf16_rne(y) << 16);
}
__device__ __forceinline__ float lo_f(unsigned g) { return __uint_as_float(g << 16); }
__device__ __forceinline__ float hi_f(unsigned g) { return __uint_as_float(g & 0xffff0000u); }

// ---------------- init: deg64 = 1.0 (self-loop) packed, count 0; scan state reset ----

__global__ void k_init(unsigned long long* __restrict__ deg64,
                       unsigned* __restrict__ ticket,
                       unsigned long long* __restrict__ chunkState,
                       int N, int nchunks) {
    int i = blockIdx.x * blockDim.x + threadIdx.x;
    if (i < N) deg64[i] = (unsigned long long)(1.0f * FIXP);
    if (i < nchunks) chunkState[i] = 0ull;
    if (i == 0) *ticket = 0u;
}

// one 64-bit atomic per edge: count in bits[40..), fixed-point val sum in bits[0..40)
__global__ void k_deg_hist(const int* __restrict__ row, const float* __restrict__ val,
                           unsigned long long* __restrict__ deg64,
                           int* __restrict__ rank, int E) {
    int e = blockIdx.x * blockDim.x + threadIdx.x;
    if (e >= E) return;
    int r = row[e];
    unsigned long long add = (1ull << 40) |
                             (unsigned long long)(val[e] * FIXP + 0.5f);
    unsigned long long old = atomicAdd(&deg64[r], add);
    rank[e] = (int)(old >> 40);
}

// ---------------- single-kernel CSR build: dinv + padded-count scan + pad fill ----
// Decoupled-lookback prefix scan over 8-padded counts; pad slots zeroed here.

__global__ __launch_bounds__(SCAN_B) void k_scan_all(const unsigned long long* __restrict__ deg64,
                                                     float* __restrict__ dinv,
                                                     int* __restrict__ rowptr,
                                                     int* __restrict__ csrOff,
                                                     float* __restrict__ csrW,
                                                     unsigned* __restrict__ ticket,
                                                     unsigned long long* __restrict__ chunkState,
                                                     int N, int nchunks) {
    __shared__ int s[SCAN_B];
    __shared__ int vc_s, exc_s;
    int t = threadIdx.x;
    if (t == 0) vc_s = (int)atomicAdd(ticket, 1u);
    __syncthreads();
    int vc = vc_s;
    int i = vc * SCAN_B + t;

    int cr = 0, c = 0;
    if (i < N) {
        unsigned long long p = deg64[i];
        cr = (int)(p >> 40);
        float deg = (float)(p & ((1ull << 40) - 1)) * (1.0f / FIXP);
        dinv[i] = rsqrtf(fmaxf(deg, 1e-12f));
        c = (cr + 7) & ~7;
    }
    s[t] = c;
    __syncthreads();
    for (int off = 1; off < SCAN_B; off <<= 1) {          // inclusive scan
        int add = (t >= off) ? s[t - off] : 0;
        __syncthreads();
        s[t] += add;
        __syncthreads();
    }
    int incl = s[t];
    int blockSum = s[SCAN_B - 1];

    if (t == 0) {
        int exc = 0;
        if (vc == 0) {
            atomicExch(&chunkState[0], FLAG_INC | (unsigned long long)(unsigned)blockSum);
        } else {
            atomicExch(&chunkState[vc], FLAG_AGG | (unsigned long long)(unsigned)blockSum);
            int j = vc - 1;
            int acc = 0;
            for (;;) {
                unsigned long long st;
                do { st = atomicAdd(&chunkState[j], 0ull); } while ((st >> 32) == 0);
                acc += (int)(st & 0xffffffffull);
                if (st & FLAG_INC) break;
                --j;
            }
            exc = acc;
            atomicExch(&chunkState[vc], FLAG_INC | (unsigned long long)(unsigned)(acc + blockSum));
        }
        exc_s = exc;
    }
    __syncthreads();
    int base = exc_s;

    if (i < N) {
        int rp = base + incl - c;       // exclusive
        rowptr[i] = rp;
        for (int k = cr; k < c; ++k) { csrOff[rp + k] = 0; csrW[rp + k] = 0.0f; }
    }
    if (vc == nchunks - 1 && t == SCAN_B - 1) rowptr[N] = base + incl;  // padded total
}

// ---------------- fused scatter + convert (SoA csr) ----------------
__global__ void k_scatter_convert(const int* __restrict__ row, const int* __restrict__ col,
                                  const float* __restrict__ val, const int* __restrict__ rank,
                                  const int* __restrict__ rowptr,
                                  int* __restrict__ csrOff, float* __restrict__ csrW,
                                  const float* __restrict__ X, const float* __restrict__ dinv,
                                  unsigned* __restrict__ Xb, int E, int NV) {
    int t = blockIdx.x * blockDim.x + threadIdx.x;
    if (t < E) {
        int r = row[t];
        int pos = rowptr[r] + rank[t];
        csrOff[pos] = col[t] << 8;          // byte offset of row in Xb (256 B/row)
        csrW[pos]   = val[t];
    } else {
        int u = t - E;
        if (u < NV) {
            float w = dinv[u >> 4];
            float4 a = ((const float4*)X)[u * 2];
            float4 b = ((const float4*)X)[u * 2 + 1];
            uint4 o;
            o.x = pack2(w * a.x, w * a.y); o.y = pack2(w * a.z, w * a.w);
            o.z = pack2(w * b.x, w * b.y); o.w = pack2(w * b.z, w * b.w);
            ((uint4*)Xb)[u] = o;
        }
    }
}

// plain scatter (f32 fallback path only)
__global__ void k_scatter(const int* __restrict__ row, const int* __restrict__ col,
                          const float* __restrict__ val, const int* __restrict__ rank,
                          const int* __restrict__ rowptr,
                          int* __restrict__ csrOff, float* __restrict__ csrW, int E) {
    int e = blockIdx.x * blockDim.x + threadIdx.x;
    if (e >= E) return;
    int r = row[e];
    int pos = rowptr[r] + rank[e];
    csrOff[pos] = col[e] << 8;
    csrW[pos]   = val[e];
}

// ---------------- SpMM row core: software-pipelined, depth-2, 8-edge blocks ----
// Issue order per step: [off(k+1) loads, gathers(k), w(k) loads] | FMA(k-1).
// vmcnt is in-order, so offsets for the NEXT block are always issued BEFORE the
// current gathers -> counted waits keep one gather block in flight while the
// previous one is accumulated (two latency chains overlapped per wave).

struct G8 { unsigned g0, g1, g2, g3, g4, g5, g6, g7; };

__device__ __forceinline__ G8 gather8(const char* __restrict__ XbB,
                                      int4 o0, int4 o1, unsigned lane4) {
    G8 r;
    r.g0 = *(const unsigned*)(XbB + (unsigned)o0.x + lane4);
    r.g1 = *(const unsigned*)(XbB + (unsigned)o0.y + lane4);
    r.g2 = *(const unsigned*)(XbB + (unsigned)o0.z + lane4);
    r.g3 = *(const unsigned*)(XbB + (unsigned)o0.w + lane4);
    r.g4 = *(const unsigned*)(XbB + (unsigned)o1.x + lane4);
    r.g5 = *(const unsigned*)(XbB + (unsigned)o1.y + lane4);
    r.g6 = *(const unsigned*)(XbB + (unsigned)o1.z + lane4);
    r.g7 = *(const unsigned*)(XbB + (unsigned)o1.w + lane4);
    return r;
}

__device__ __forceinline__ void acc8(const G8& g, float4 w0, float4 w1,
                                     float2& a0, float2& a1, float2& a2, float2& a3) {
    a0.x += w0.x * lo_f(g.g0); a0.y += w0.x * hi_f(g.g0);
    a1.x += w0.y * lo_f(g.g1); a1.y += w0.y * hi_f(g.g1);
    a2.x += w0.z * lo_f(g.g2); a2.y += w0.z * hi_f(g.g2);
    a3.x += w0.w * lo_f(g.g3); a3.y += w0.w * hi_f(g.g3);
    a0.x += w1.x * lo_f(g.g4); a0.y += w1.x * hi_f(g.g4);
    a1.x += w1.y * lo_f(g.g5); a1.y += w1.y * hi_f(g.g5);
    a2.x += w1.z * lo_f(g.g6); a2.y += w1.z * hi_f(g.g6);
    a3.x += w1.w * lo_f(g.g7); a3.y += w1.w * hi_f(g.g7);
}

__device__ __forceinline__ float2 spmm_row_bf16(const int* __restrict__ rowptr,
                                                const int* __restrict__ csrOff,
                                                const float* __restrict__ csrW,
                                                const char* __restrict__ XbB,
                                                int rowi, int lane) {
    const unsigned lane4 = (unsigned)lane << 2;
    unsigned gs = *(const unsigned*)(XbB + ((unsigned)rowi << 8) + lane4);
    float2 a0 = make_float2(lo_f(gs), hi_f(gs));   // self term, weight 1
    float2 a1 = make_float2(0.f, 0.f), a2 = make_float2(0.f, 0.f), a3 = make_float2(0.f, 0.f);
    int e  = rowptr[rowi];
    int e1 = rowptr[rowi + 1];                     // (e1-e) % 8 == 0 by padding
    int nb = (e1 - e) >> 3;

    if (nb > 0) {
        const int4*   op = (const int4*)(csrOff + e);   // block j: op[2j], op[2j+1]
        const float4* wp = (const float4*)(csrW + e);

        // prologue: block 0 gathers + weights; block 1 offsets prefetched
        int4 oA0 = op[0], oA1 = op[1];
        G8 gA = gather8(XbB, oA0, oA1, lane4);
        float4 wA0 = wp[0], wA1 = wp[1];
        int4 oB0 = op[2], oB1 = op[3];               // guard-safe when nb==1

        int k = 1;
        for (; k + 1 < nb; k += 2) {
            // stepB: gather block k, acc block k-1
            int4 nA0 = op[2 * k + 2], nA1 = op[2 * k + 3];   // offsets block k+1
            G8 gB = gather8(XbB, oB0, oB1, lane4);
            float4 wB0 = wp[2 * k], wB1 = wp[2 * k + 1];
            __builtin_amdgcn_sched_barrier(0);
            acc8(gA, wA0, wA1, a0, a1, a2, a3);
            // stepA: gather block k+1, acc block k
            oB0 = op[2 * k + 4]; oB1 = op[2 * k + 5];        // offsets block k+2 (guard)
            gA = gather8(XbB, nA0, nA1, lane4);
            wA0 = wp[2 * k + 2]; wA1 = wp[2 * k + 3];
            __builtin_amdgcn_sched_barrier(0);
            acc8(gB, wB0, wB1, a0, a1, a2, a3);
        }
        if (k < nb) {                                        // one trailing block
            G8 gB = gather8(XbB, oB0, oB1, lane4);
            float4 wB0 = wp[2 * k], wB1 = wp[2 * k + 1];
            __builtin_amdgcn_sched_barrier(0);
            acc8(gA, wA0, wA1, a0, a1, a2, a3);
            acc8(gB, wB0, wB1, a0, a1, a2, a3);
        } else {
            acc8(gA, wA0, wA1, a0, a1, a2, a3);
        }
    }
    float2 acc;
    acc.x = (a0.x + a1.x) + (a2.x + a3.x);
    acc.y = (a0.y + a1.y) + (a2.y + a3.y);
    return acc;
}

// ---------------- concrete SpMM kernels ----------------

__global__ __launch_bounds__(256) void k_spmm_l1(const int* __restrict__ rowptr,
                                                 const int* __restrict__ csrOff,
                                                 const float* __restrict__ csrW,
                                                 const float* __restrict__ dinv,
                                                 const unsigned* __restrict__ Xb,
                                                 float* __restrict__ Xout,
                                                 unsigned* __restrict__ XbOut, int N) {
    int lane = threadIdx.x & 63;
    int wid  = threadIdx.x >> 6;
    int rowi = blockIdx.x * 4 + wid;
    if (rowi >= N) return;
    float2 acc = spmm_row_bf16(rowptr, csrOff, csrW, (const char*)Xb, rowi, lane);
    float dr = dinv[rowi];
    float2 x1 = make_float2(dr * acc.x, dr * acc.y);
    ((float2*)Xout)[(size_t)rowi * 64 + lane] = x1;
    XbOut[((unsigned)rowi << 6) | lane] = pack2(dr * x1.x, dr * x1.y);  // prescaled for layer 2
}

// head: lin staged in LDS (proven config)
__global__ __launch_bounds__(256) void k_spmm_l2_head(const int* __restrict__ rowptr,
                                                      const int* __restrict__ csrOff,
                                                      const float* __restrict__ csrW,
                                                      const float* __restrict__ dinv,
                                                      const unsigned* __restrict__ Xb,
                                                      float* __restrict__ Xout,
                                                      const float* __restrict__ lin,
                                                      float* __restrict__ lsm,
                                                      float* __restrict__ logits,
                                                      int N, int C) {
    __shared__ float lin_s[D_FEAT * C_MAX];
    __shared__ float xs[4][D_FEAT];
    int lane = threadIdx.x & 63;
    int wid  = threadIdx.x >> 6;
    int rowi = blockIdx.x * 4 + wid;

    for (int i = threadIdx.x; i < D_FEAT * C; i += 256) lin_s[i] = lin[i];

    if (rowi < N) {
        float2 acc = spmm_row_bf16(rowptr, csrOff, csrW, (const char*)Xb, rowi, lane);
        float dr = dinv[rowi];
        float2 x2 = make_float2(dr * acc.x, dr * acc.y);
        ((float2*)Xout)[(size_t)rowi * 64 + lane] = x2;
        xs[wid][2 * lane]     = x2.x;
        xs[wid][2 * lane + 1] = x2.y;
    }
    __syncthreads();
    if (rowi >= N) return;

    float a = 0.0f;
    if (lane < C) {
#pragma unroll 8
        for (int d = 0; d < D_FEAT; ++d)
            a += xs[wid][d] * lin_s[d * C + lane];
    }
    float m = (lane < C) ? a : -INFINITY;
    for (int off = 32; off; off >>= 1) m = fmaxf(m, __shfl_xor(m, off));
    float ev = (lane < C) ? __expf(a - m) : 0.0f;
    float s = ev;
    for (int off = 32; off; off >>= 1) s += __shfl_xor(s, off);
    float lse = m + logf(s);
    if (lane < C) {
        logits[(size_t)rowi * C + lane] = a;
        lsm[(size_t)rowi * C + lane]    = a - lse;
    }
}

// ---------------- f32 fallback (only if workspace can't fit bf16 mirrors) ----------------

__global__ __launch_bounds__(256) void k_spmm_f32(const int* __restrict__ rowptr,
                                                  const int* __restrict__ csrOff,
                                                  const float* __restrict__ csrW,
                                                  const float* __restrict__ dinv,
                                                  const float* __restrict__ Xin,
                                                  float* __restrict__ Xout, int N) {
    int lane = threadIdx.x & 63;
    int wid  = threadIdx.x >> 6;
    int rowi = blockIdx.x * 4 + wid;
    if (rowi >= N) return;
    const float2* Xin2 = (const float2*)Xin;
    float dr = dinv[rowi];
    float2 v0 = Xin2[(size_t)rowi * 64 + lane];
    float2 a0 = make_float2(dr * v0.x, dr * v0.y);   // self: dinv_r * X_r (pre final scale)
    float2 a1 = make_float2(0.f, 0.f);
    int e  = rowptr[rowi];
    int e1 = rowptr[rowi + 1];
    for (; e < e1; e += 2) {
        unsigned c0 = (unsigned)csrOff[e] >> 8, c1 = (unsigned)csrOff[e + 1] >> 8;
        float w0 = csrW[e] * dinv[c0];
        float w1 = csrW[e + 1] * dinv[c1];
        float2 g0 = Xin2[(size_t)c0 * 64 + lane];
        float2 g1 = Xin2[(size_t)c1 * 64 + lane];
        a0.x += w0 * g0.x; a0.y += w0 * g0.y;
        a1.x += w1 * g1.x; a1.y += w1 * g1.y;
    }
    float2 acc = make_float2(dr * (a0.x + a1.x), dr * (a0.y + a1.y));
    ((float2*)Xout)[(size_t)rowi * 64 + lane] = acc;
}

__global__ __launch_bounds__(256) void k_head(const float* __restrict__ X,
                                              const float* __restrict__ lin,
                                              float* __restrict__ lsm,
                                              float* __restrict__ logits,
                                              int N, int C) {
    __shared__ float xs[4][D_FEAT];
    int lane = threadIdx.x & 63;
    int wid  = threadIdx.x >> 6;
    int node = blockIdx.x * 4 + wid;
    if (node < N) {
        xs[wid][lane]      = X[(size_t)node * D_FEAT + lane];
        xs[wid][lane + 64] = X[(size_t)node * D_FEAT + 64 + lane];
    }
    __syncthreads();
    if (node >= N) return;

    float acc = 0.0f;
    if (lane < C) {
        for (int d = 0; d < D_FEAT; ++d)
            acc += xs[wid][d] * lin[d * C + lane];
    }
    float m = (lane < C) ? acc : -INFINITY;
    for (int off = 32; off; off >>= 1) m = fmaxf(m, __shfl_xor(m, off));
    float ev = (lane < C) ? __expf(acc - m) : 0.0f;
    float s = ev;
    for (int off = 32; off; off >>= 1) s += __shfl_xor(s, off);
    float lse = m + logf(s);
    if (lane < C) {
        logits[(size_t)node * C + lane] = acc;
        lsm[(size_t)node * C + lane]    = acc - lse;
    }
}

// ---------------- launch ----------------

extern "C" void kernel_launch(void* const* d_in, const int* in_sizes, int n_in,
                              void* d_out, int out_size, void* d_ws, size_t ws_size,
                              hipStream_t stream) {
    const float* features = (const float*)d_in[0];
    const int*   adj_row  = (const int*)d_in[1];
    const int*   adj_col  = (const int*)d_in[2];
    const float* adj_val  = (const float*)d_in[3];
    const float* lin      = (const float*)d_in[4];

    const int N = in_sizes[0] / D_FEAT;
    const int E = in_sizes[1];
    const int C = in_sizes[4] / D_FEAT;
    const int csrTot = E + 8 * N + 16;   // worst-case padded edge count + prefetch guard
    const int nchunks = (N + SCAN_B - 1) / SCAN_B;

    float* out = (float*)d_out;
    const size_t NC = (size_t)N * C;
    const size_t ND = (size_t)N * D_FEAT;
    float* lsm    = out;
    float* logits = out + NC;
    float* X1     = out + 2 * NC;
    float* X2     = out + 2 * NC + ND;

    // workspace layout (16B-aligned chunks)
    char* wp = (char*)d_ws;
    auto alloc = [&](size_t bytes) { char* p = wp; wp += (bytes + 15) & ~(size_t)15; return p; };
    unsigned long long* deg64      = (unsigned long long*)alloc((size_t)N * 8);
    float*              dinv       = (float*)alloc((size_t)N * 4);
    int*                rowptr     = (int*)alloc((size_t)(N + 1) * 4);
    unsigned*           ticket     = (unsigned*)alloc(16);
    unsigned long long* chunkState = (unsigned long long*)alloc((size_t)nchunks * 8);
    int*                rank       = (int*)alloc((size_t)E * 4);
    int*                csrOff     = (int*)alloc((size_t)csrTot * 4);
    float*              csrW       = (float*)alloc((size_t)csrTot * 4);
    unsigned*           Xb0        = (unsigned*)alloc((size_t)N * (D_FEAT / 2) * 4);
    unsigned*           Xb1        = (unsigned*)alloc((size_t)N * (D_FEAT / 2) * 4);

    const bool bf16_ok = ((size_t)(wp - (char*)d_ws) <= ws_size) && (C <= C_MAX);

    const int B = 256;

    k_init<<<(N + B - 1) / B, B, 0, stream>>>(deg64, ticket, chunkState, N, nchunks);
    k_deg_hist<<<(E + B - 1) / B, B, 0, stream>>>(adj_row, adj_val, deg64, rank, E);
    k_scan_all<<<nchunks, SCAN_B, 0, stream>>>(deg64, dinv, rowptr, csrOff, csrW,
                                               ticket, chunkState, N, nchunks);

    if (bf16_ok) {
        const int NV = N * (D_FEAT / 8);     // uint4 convert items
        k_scatter_convert<<<(E + NV + B - 1) / B, B, 0, stream>>>(adj_row, adj_col, adj_val,
                                                                  rank, rowptr, csrOff, csrW,
                                                                  features, dinv, Xb0, E, NV);
        int spmmBlocks = (N + 3) / 4;
        k_spmm_l1<<<spmmBlocks, 256, 0, stream>>>(rowptr, csrOff, csrW, dinv, Xb0, X1, Xb1, N);
        k_spmm_l2_head<<<spmmBlocks, 256, 0, stream>>>(rowptr, csrOff, csrW, dinv, Xb1, X2,
                                                       lin, lsm, logits, N, C);
    } else {
        k_scatter<<<(E + B - 1) / B, B, 0, stream>>>(adj_row, adj_col, adj_val, rank,
                                                     rowptr, csrOff, csrW, E);
        int spmmBlocks = (N + 3) / 4;
        k_spmm_f32<<<spmmBlocks, 256, 0, stream>>>(rowptr, csrOff, csrW, dinv, features, X1, N);
        k_spmm_f32<<<spmmBlocks, 256, 0, stream>>>(rowptr, csrOff, csrW, dinv, X1, X2, N);
        k_head<<<(N + 3) / 4, 256, 0, stream>>>(X2, lin, lsm, logits, N, C);
    }
}

// Round 7
// 187.281 us; speedup vs baseline: 1.1657x; 1.1657x over previous
//
#include <hip/hip_runtime.h>
#include <math.h>

#define D_FEAT 128
#define SCAN_B 256
#define C_MAX  40
#define FIXP   33554432.0f   // 2^25 fixed-point scale for packed degree sum

#define FLAG_AGG (1ull << 32)
#define FLAG_INC (2ull << 32)

typedef int   v4i __attribute__((ext_vector_type(4)));
typedef float v2f __attribute__((ext_vector_type(2)));

// ---------------- bf16 helpers ----------------

__device__ __forceinline__ unsigned bf16_rne(float x) {
    unsigned u = __float_as_uint(x);
    return (u + 0x7fffu + ((u >> 16) & 1u)) >> 16;
}
__device__ __forceinline__ unsigned pack2(float x, float y) {
    return bf16_rne(x) | (bf16_rne(y) << 16);
}
__device__ __forceinline__ float lo_f(unsigned g) { return __uint_as_float(g << 16); }
__device__ __forceinline__ float hi_f(unsigned g) { return __uint_as_float(g & 0xffff0000u); }

__device__ __forceinline__ void nt_store2(float* base, size_t idx, float x, float y) {
    v2f t; t.x = x; t.y = y;
    __builtin_nontemporal_store(t, (v2f*)base + idx);
}

// ---------------- init: deg64 = 1.0 (self-loop) packed, count 0; scan state reset ----

__global__ void k_init(unsigned long long* __restrict__ deg64,
                       unsigned* __restrict__ ticket,
                       unsigned long long* __restrict__ chunkState,
                       int N, int nchunks) {
    int i = blockIdx.x * blockDim.x + threadIdx.x;
    if (i < N) deg64[i] = (unsigned long long)(1.0f * FIXP);
    if (i < nchunks) chunkState[i] = 0ull;
    if (i == 0) *ticket = 0u;
}

// one 64-bit atomic per edge: count in bits[40..), fixed-point val sum in bits[0..40)
__global__ void k_deg_hist(const int* __restrict__ row, const float* __restrict__ val,
                           unsigned long long* __restrict__ deg64,
                           int* __restrict__ rank, int E) {
    int e = blockIdx.x * blockDim.x + threadIdx.x;
    if (e >= E) return;
    int r = row[e];
    unsigned long long add = (1ull << 40) |
                             (unsigned long long)(val[e] * FIXP + 0.5f);
    unsigned long long old = atomicAdd(&deg64[r], add);
    rank[e] = (int)(old >> 40);
}

// ---------------- single-kernel CSR build: dinv + padded-count scan + pad fill ----
// Decoupled-lookback prefix scan over 8-padded counts; pad slots zeroed here.

__global__ __launch_bounds__(SCAN_B) void k_scan_all(const unsigned long long* __restrict__ deg64,
                                                     float* __restrict__ dinv,
                                                     int* __restrict__ rowptr,
                                                     int2* __restrict__ csr,
                                                     unsigned* __restrict__ ticket,
                                                     unsigned long long* __restrict__ chunkState,
                                                     int N, int nchunks) {
    __shared__ int s[SCAN_B];
    __shared__ int vc_s, exc_s;
    int t = threadIdx.x;
    if (t == 0) vc_s = (int)atomicAdd(ticket, 1u);
    __syncthreads();
    int vc = vc_s;
    int i = vc * SCAN_B + t;

    int cr = 0, c = 0;
    if (i < N) {
        unsigned long long p = deg64[i];
        cr = (int)(p >> 40);
        float deg = (float)(p & ((1ull << 40) - 1)) * (1.0f / FIXP);
        dinv[i] = rsqrtf(fmaxf(deg, 1e-12f));
        c = (cr + 7) & ~7;
    }
    s[t] = c;
    __syncthreads();
    for (int off = 1; off < SCAN_B; off <<= 1) {          // inclusive scan
        int add = (t >= off) ? s[t - off] : 0;
        __syncthreads();
        s[t] += add;
        __syncthreads();
    }
    int incl = s[t];
    int blockSum = s[SCAN_B - 1];

    if (t == 0) {
        int exc = 0;
        if (vc == 0) {
            atomicExch(&chunkState[0], FLAG_INC | (unsigned long long)(unsigned)blockSum);
        } else {
            atomicExch(&chunkState[vc], FLAG_AGG | (unsigned long long)(unsigned)blockSum);
            int j = vc - 1;
            int acc = 0;
            for (;;) {
                unsigned long long st;
                do { st = atomicAdd(&chunkState[j], 0ull); } while ((st >> 32) == 0);
                acc += (int)(st & 0xffffffffull);
                if (st & FLAG_INC) break;
                --j;
            }
            exc = acc;
            atomicExch(&chunkState[vc], FLAG_INC | (unsigned long long)(unsigned)(acc + blockSum));
        }
        exc_s = exc;
    }
    __syncthreads();
    int base = exc_s;

    if (i < N) {
        int rp = base + incl - c;       // exclusive
        rowptr[i] = rp;
        for (int k = cr; k < c; ++k) csr[rp + k] = make_int2(0, 0);   // zero pads
    }
    if (vc == nchunks - 1 && t == SCAN_B - 1) rowptr[N] = base + incl;  // padded total
}

// ---------------- fused scatter + convert ----------------
__global__ void k_scatter_convert(const int* __restrict__ row, const int* __restrict__ col,
                                  const float* __restrict__ val, const int* __restrict__ rank,
                                  const int* __restrict__ rowptr, int2* __restrict__ csr,
                                  const float* __restrict__ X, const float* __restrict__ dinv,
                                  unsigned* __restrict__ Xb, int E, int NV) {
    int t = blockIdx.x * blockDim.x + threadIdx.x;
    if (t < E) {
        int r = row[t];
        csr[rowptr[r] + rank[t]] = make_int2(col[t] << 8, __float_as_int(val[t]));
    } else {
        int u = t - E;
        if (u < NV) {
            float w = dinv[u >> 4];
            float4 a = ((const float4*)X)[u * 2];
            float4 b = ((const float4*)X)[u * 2 + 1];
            uint4 o;
            o.x = pack2(w * a.x, w * a.y); o.y = pack2(w * a.z, w * a.w);
            o.z = pack2(w * b.x, w * b.y); o.w = pack2(w * b.z, w * b.w);
            ((uint4*)Xb)[u] = o;
        }
    }
}

// plain scatter (f32 fallback path only)
__global__ void k_scatter(const int* __restrict__ row, const int* __restrict__ col,
                          const float* __restrict__ val, const int* __restrict__ rank,
                          const int* __restrict__ rowptr, int2* __restrict__ csr, int E) {
    int e = blockIdx.x * blockDim.x + threadIdx.x;
    if (e >= E) return;
    int r = row[e];
    csr[rowptr[r] + rank[e]] = make_int2(col[e] << 8, __float_as_int(val[e]));
}

// ---------------- SpMM row core (single row/wave, 16-deep, byte offsets) ------
// Wave = 1 row, lane i holds feature dword i (2 bf16). 1-dword/lane gathers are
// fully coalesced (256 B/instruction); 16 gathers in flight in the main block.
// CSR loads are NON-TEMPORAL (pure stream, 8.4 MB/pass) so they don't evict Xb
// gather lines from L2.

__device__ __forceinline__ float2 spmm_row_bf16(const int* __restrict__ rowptr,
                                                const int2* __restrict__ csr,
                                                const char* __restrict__ XbB,
                                                int rowi, int lane) {
    const unsigned lane4 = (unsigned)lane << 2;
    unsigned gs = *(const unsigned*)(XbB + ((unsigned)rowi << 8) + lane4);
    float2 a0 = make_float2(lo_f(gs), hi_f(gs));   // self term, weight 1
    float2 a1 = make_float2(0.f, 0.f), a2 = make_float2(0.f, 0.f), a3 = make_float2(0.f, 0.f);
    int e  = rowptr[rowi];
    int e1 = rowptr[rowi + 1];                     // (e1-e) % 8 == 0 by padding

    // main: 16 edges / iteration (16 outstanding gathers)
    for (; e + 16 <= e1; e += 16) {
        const v4i* cp = (const v4i*)(csr + e);
        v4i q0 = __builtin_nontemporal_load(cp + 0);
        v4i q1 = __builtin_nontemporal_load(cp + 1);
        v4i q2 = __builtin_nontemporal_load(cp + 2);
        v4i q3 = __builtin_nontemporal_load(cp + 3);
        v4i q4 = __builtin_nontemporal_load(cp + 4);
        v4i q5 = __builtin_nontemporal_load(cp + 5);
        v4i q6 = __builtin_nontemporal_load(cp + 6);
        v4i q7 = __builtin_nontemporal_load(cp + 7);
        unsigned g0 = *(const unsigned*)(XbB + (unsigned)q0.x + lane4);
        unsigned g1 = *(const unsigned*)(XbB + (unsigned)q0.z + lane4);
        unsigned g2 = *(const unsigned*)(XbB + (unsigned)q1.x + lane4);
        unsigned g3 = *(const unsigned*)(XbB + (unsigned)q1.z + lane4);
        unsigned g4 = *(const unsigned*)(XbB + (unsigned)q2.x + lane4);
        unsigned g5 = *(const unsigned*)(XbB + (unsigned)q2.z + lane4);
        unsigned g6 = *(const unsigned*)(XbB + (unsigned)q3.x + lane4);
        unsigned g7 = *(const unsigned*)(XbB + (unsigned)q3.z + lane4);
        unsigned g8 = *(const unsigned*)(XbB + (unsigned)q4.x + lane4);
        unsigned g9 = *(const unsigned*)(XbB + (unsigned)q4.z + lane4);
        unsigned ga = *(const unsigned*)(XbB + (unsigned)q5.x + lane4);
        unsigned gb = *(const unsigned*)(XbB + (unsigned)q5.z + lane4);
        unsigned gc = *(const unsigned*)(XbB + (unsigned)q6.x + lane4);
        unsigned gd = *(const unsigned*)(XbB + (unsigned)q6.z + lane4);
        unsigned ge = *(const unsigned*)(XbB + (unsigned)q7.x + lane4);
        unsigned gf = *(const unsigned*)(XbB + (unsigned)q7.z + lane4);
        float w0 = __int_as_float(q0.y), w1 = __int_as_float(q0.w);
        float w2 = __int_as_float(q1.y), w3 = __int_as_float(q1.w);
        float w4 = __int_as_float(q2.y), w5 = __int_as_float(q2.w);
        float w6 = __int_as_float(q3.y), w7 = __int_as_float(q3.w);
        float w8 = __int_as_float(q4.y), w9 = __int_as_float(q4.w);
        float wa = __int_as_float(q5.y), wb = __int_as_float(q5.w);
        float wc = __int_as_float(q6.y), wd = __int_as_float(q6.w);
        float we = __int_as_float(q7.y), wf = __int_as_float(q7.w);
        a0.x += w0 * lo_f(g0); a0.y += w0 * hi_f(g0);
        a1.x += w1 * lo_f(g1); a1.y += w1 * hi_f(g1);
        a2.x += w2 * lo_f(g2); a2.y += w2 * hi_f(g2);
        a3.x += w3 * lo_f(g3); a3.y += w3 * hi_f(g3);
        a0.x += w4 * lo_f(g4); a0.y += w4 * hi_f(g4);
        a1.x += w5 * lo_f(g5); a1.y += w5 * hi_f(g5);
        a2.x += w6 * lo_f(g6); a2.y += w6 * hi_f(g6);
        a3.x += w7 * lo_f(g7); a3.y += w7 * hi_f(g7);
        a0.x += w8 * lo_f(g8); a0.y += w8 * hi_f(g8);
        a1.x += w9 * lo_f(g9); a1.y += w9 * hi_f(g9);
        a2.x += wa * lo_f(ga); a2.y += wa * hi_f(ga);
        a3.x += wb * lo_f(gb); a3.y += wb * hi_f(gb);
        a0.x += wc * lo_f(gc); a0.y += wc * hi_f(gc);
        a1.x += wd * lo_f(gd); a1.y += wd * hi_f(gd);
        a2.x += we * lo_f(ge); a2.y += we * hi_f(ge);
        a3.x += wf * lo_f(gf); a3.y += wf * hi_f(gf);
    }
    // remainder: exactly 0 or 8 edges
    if (e < e1) {
        const v4i* cp = (const v4i*)(csr + e);
        v4i q0 = __builtin_nontemporal_load(cp + 0);
        v4i q1 = __builtin_nontemporal_load(cp + 1);
        v4i q2 = __builtin_nontemporal_load(cp + 2);
        v4i q3 = __builtin_nontemporal_load(cp + 3);
        unsigned g0 = *(const unsigned*)(XbB + (unsigned)q0.x + lane4);
        unsigned g1 = *(const unsigned*)(XbB + (unsigned)q0.z + lane4);
        unsigned g2 = *(const unsigned*)(XbB + (unsigned)q1.x + lane4);
        unsigned g3 = *(const unsigned*)(XbB + (unsigned)q1.z + lane4);
        unsigned g4 = *(const unsigned*)(XbB + (unsigned)q2.x + lane4);
        unsigned g5 = *(const unsigned*)(XbB + (unsigned)q2.z + lane4);
        unsigned g6 = *(const unsigned*)(XbB + (unsigned)q3.x + lane4);
        unsigned g7 = *(const unsigned*)(XbB + (unsigned)q3.z + lane4);
        float w0 = __int_as_float(q0.y), w1 = __int_as_float(q0.w);
        float w2 = __int_as_float(q1.y), w3 = __int_as_float(q1.w);
        float w4 = __int_as_float(q2.y), w5 = __int_as_float(q2.w);
        float w6 = __int_as_float(q3.y), w7 = __int_as_float(q3.w);
        a0.x += w0 * lo_f(g0); a0.y += w0 * hi_f(g0);
        a1.x += w1 * lo_f(g1); a1.y += w1 * hi_f(g1);
        a2.x += w2 * lo_f(g2); a2.y += w2 * hi_f(g2);
        a3.x += w3 * lo_f(g3); a3.y += w3 * hi_f(g3);
        a0.x += w4 * lo_f(g4); a0.y += w4 * hi_f(g4);
        a1.x += w5 * lo_f(g5); a1.y += w5 * hi_f(g5);
        a2.x += w6 * lo_f(g6); a2.y += w6 * hi_f(g6);
        a3.x += w7 * lo_f(g7); a3.y += w7 * hi_f(g7);
    }
    float2 acc;
    acc.x = (a0.x + a1.x) + (a2.x + a3.x);
    acc.y = (a0.y + a1.y) + (a2.y + a3.y);
    return acc;
}

// ---------------- concrete SpMM kernels ----------------

__global__ __launch_bounds__(256) void k_spmm_l1(const int* __restrict__ rowptr,
                                                 const int2* __restrict__ csr,
                                                 const float* __restrict__ dinv,
                                                 const unsigned* __restrict__ Xb,
                                                 float* __restrict__ Xout,
                                                 unsigned* __restrict__ XbOut, int N) {
    int lane = threadIdx.x & 63;
    int wid  = threadIdx.x >> 6;
    int rowi = blockIdx.x * 4 + wid;
    if (rowi >= N) return;
    float2 acc = spmm_row_bf16(rowptr, csr, (const char*)Xb, rowi, lane);
    float dr = dinv[rowi];
    float2 x1 = make_float2(dr * acc.x, dr * acc.y);
    nt_store2(Xout, (size_t)rowi * 64 + lane, x1.x, x1.y);          // write-once stream
    XbOut[((unsigned)rowi << 6) | lane] = pack2(dr * x1.x, dr * x1.y);  // re-read next kernel: temporal
}

// head: lin staged in LDS (proven config); output stores non-temporal
__global__ __launch_bounds__(256) void k_spmm_l2_head(const int* __restrict__ rowptr,
                                                      const int2* __restrict__ csr,
                                                      const float* __restrict__ dinv,
                                                      const unsigned* __restrict__ Xb,
                                                      float* __restrict__ Xout,
                                                      const float* __restrict__ lin,
                                                      float* __restrict__ lsm,
                                                      float* __restrict__ logits,
                                                      int N, int C) {
    __shared__ float lin_s[D_FEAT * C_MAX];
    __shared__ float xs[4][D_FEAT];
    int lane = threadIdx.x & 63;
    int wid  = threadIdx.x >> 6;
    int rowi = blockIdx.x * 4 + wid;

    for (int i = threadIdx.x; i < D_FEAT * C; i += 256) lin_s[i] = lin[i];

    if (rowi < N) {
        float2 acc = spmm_row_bf16(rowptr, csr, (const char*)Xb, rowi, lane);
        float dr = dinv[rowi];
        float2 x2 = make_float2(dr * acc.x, dr * acc.y);
        nt_store2(Xout, (size_t)rowi * 64 + lane, x2.x, x2.y);
        xs[wid][2 * lane]     = x2.x;
        xs[wid][2 * lane + 1] = x2.y;
    }
    __syncthreads();
    if (rowi >= N) return;

    float a = 0.0f;
    if (lane < C) {
#pragma unroll 8
        for (int d = 0; d < D_FEAT; ++d)
            a += xs[wid][d] * lin_s[d * C + lane];
    }
    float m = (lane < C) ? a : -INFINITY;
    for (int off = 32; off; off >>= 1) m = fmaxf(m, __shfl_xor(m, off));
    float ev = (lane < C) ? __expf(a - m) : 0.0f;
    float s = ev;
    for (int off = 32; off; off >>= 1) s += __shfl_xor(s, off);
    float lse = m + logf(s);
    if (lane < C) {
        __builtin_nontemporal_store(a,       &logits[(size_t)rowi * C + lane]);
        __builtin_nontemporal_store(a - lse, &lsm[(size_t)rowi * C + lane]);
    }
}

// ---------------- f32 fallback (only if workspace can't fit bf16 mirrors) ----------------

__global__ __launch_bounds__(256) void k_spmm_f32(const int* __restrict__ rowptr,
                                                  const int2* __restrict__ csr,
                                                  const float* __restrict__ dinv,
                                                  const float* __restrict__ Xin,
                                                  float* __restrict__ Xout, int N) {
    int lane = threadIdx.x & 63;
    int wid  = threadIdx.x >> 6;
    int rowi = blockIdx.x * 4 + wid;
    if (rowi >= N) return;
    const float2* Xin2 = (const float2*)Xin;
    float dr = dinv[rowi];
    float2 v0 = Xin2[(size_t)rowi * 64 + lane];
    float2 a0 = make_float2(dr * v0.x, dr * v0.y);   // self: dinv_r * X_r (pre final scale)
    float2 a1 = make_float2(0.f, 0.f);
    int e  = rowptr[rowi];
    int e1 = rowptr[rowi + 1];
    for (; e < e1; e += 2) {
        int2 q0 = csr[e], q1 = csr[e + 1];
        unsigned c0 = (unsigned)q0.x >> 8, c1 = (unsigned)q1.x >> 8;
        float w0 = __int_as_float(q0.y) * dinv[c0];
        float w1 = __int_as_float(q1.y) * dinv[c1];
        float2 g0 = Xin2[(size_t)c0 * 64 + lane];
        float2 g1 = Xin2[(size_t)c1 * 64 + lane];
        a0.x += w0 * g0.x; a0.y += w0 * g0.y;
        a1.x += w1 * g1.x; a1.y += w1 * g1.y;
    }
    float2 acc = make_float2(dr * (a0.x + a1.x), dr * (a0.y + a1.y));
    ((float2*)Xout)[(size_t)rowi * 64 + lane] = acc;
}

__global__ __launch_bounds__(256) void k_head(const float* __restrict__ X,
                                              const float* __restrict__ lin,
                                              float* __restrict__ lsm,
                                              float* __restrict__ logits,
                                              int N, int C) {
    __shared__ float xs[4][D_FEAT];
    int lane = threadIdx.x & 63;
    int wid  = threadIdx.x >> 6;
    int node = blockIdx.x * 4 + wid;
    if (node < N) {
        xs[wid][lane]      = X[(size_t)node * D_FEAT + lane];
        xs[wid][lane + 64] = X[(size_t)node * D_FEAT + 64 + lane];
    }
    __syncthreads();
    if (node >= N) return;

    float acc = 0.0f;
    if (lane < C) {
        for (int d = 0; d < D_FEAT; ++d)
            acc += xs[wid][d] * lin[d * C + lane];
    }
    float m = (lane < C) ? acc : -INFINITY;
    for (int off = 32; off; off >>= 1) m = fmaxf(m, __shfl_xor(m, off));
    float ev = (lane < C) ? __expf(acc - m) : 0.0f;
    float s = ev;
    for (int off = 32; off; off >>= 1) s += __shfl_xor(s, off);
    float lse = m + logf(s);
    if (lane < C) {
        logits[(size_t)node * C + lane] = acc;
        lsm[(size_t)node * C + lane]    = acc - lse;
    }
}

// ---------------- launch ----------------

extern "C" void kernel_launch(void* const* d_in, const int* in_sizes, int n_in,
                              void* d_out, int out_size, void* d_ws, size_t ws_size,
                              hipStream_t stream) {
    const float* features = (const float*)d_in[0];
    const int*   adj_row  = (const int*)d_in[1];
    const int*   adj_col  = (const int*)d_in[2];
    const float* adj_val  = (const float*)d_in[3];
    const float* lin      = (const float*)d_in[4];

    const int N = in_sizes[0] / D_FEAT;
    const int E = in_sizes[1];
    const int C = in_sizes[4] / D_FEAT;
    const int csrTot = E + 8 * N;   // worst-case padded edge count
    const int nchunks = (N + SCAN_B - 1) / SCAN_B;

    float* out = (float*)d_out;
    const size_t NC = (size_t)N * C;
    const size_t ND = (size_t)N * D_FEAT;
    float* lsm    = out;
    float* logits = out + NC;
    float* X1     = out + 2 * NC;
    float* X2     = out + 2 * NC + ND;

    // workspace layout (16B-aligned chunks)
    char* wp = (char*)d_ws;
    auto alloc = [&](size_t bytes) { char* p = wp; wp += (bytes + 15) & ~(size_t)15; return p; };
    unsigned long long* deg64      = (unsigned long long*)alloc((size_t)N * 8);
    float*              dinv       = (float*)alloc((size_t)N * 4);
    int*                rowptr     = (int*)alloc((size_t)(N + 1) * 4);
    unsigned*           ticket     = (unsigned*)alloc(16);
    unsigned long long* chunkState = (unsigned long long*)alloc((size_t)nchunks * 8);
    int*                rank       = (int*)alloc((size_t)E * 4);
    int2*               csr        = (int2*)alloc((size_t)csrTot * 8);
    unsigned*           Xb0        = (unsigned*)alloc((size_t)N * (D_FEAT / 2) * 4);
    unsigned*           Xb1        = (unsigned*)alloc((size_t)N * (D_FEAT / 2) * 4);

    const bool bf16_ok = ((size_t)(wp - (char*)d_ws) <= ws_size) && (C <= C_MAX);

    const int B = 256;

    k_init<<<(N + B - 1) / B, B, 0, stream>>>(deg64, ticket, chunkState, N, nchunks);
    k_deg_hist<<<(E + B - 1) / B, B, 0, stream>>>(adj_row, adj_val, deg64, rank, E);
    k_scan_all<<<nchunks, SCAN_B, 0, stream>>>(deg64, dinv, rowptr, csr,
                                               ticket, chunkState, N, nchunks);

    if (bf16_ok) {
        const int NV = N * (D_FEAT / 8);     // uint4 convert items
        k_scatter_convert<<<(E + NV + B - 1) / B, B, 0, stream>>>(adj_row, adj_col, adj_val,
                                                                  rank, rowptr, csr,
                                                                  features, dinv, Xb0, E, NV);
        int spmmBlocks = (N + 3) / 4;
        k_spmm_l1<<<spmmBlocks, 256, 0, stream>>>(rowptr, csr, dinv, Xb0, X1, Xb1, N);
        k_spmm_l2_head<<<spmmBlocks, 256, 0, stream>>>(rowptr, csr, dinv, Xb1, X2,
                                                       lin, lsm, logits, N, C);
    } else {
        k_scatter<<<(E + B - 1) / B, B, 0, stream>>>(adj_row, adj_col, adj_val, rank,
                                                     rowptr, csr, E);
        int spmmBlocks = (N + 3) / 4;
        k_spmm_f32<<<spmmBlocks, 256, 0, stream>>>(rowptr, csr, dinv, features, X1, N);
        k_spmm_f32<<<spmmBlocks, 256, 0, stream>>>(rowptr, csr, dinv, X1, X2, N);
        k_head<<<(N + 3) / 4, 256, 0, stream>>>(X2, lin, lsm, logits, N, C);
    }
}

// Round 8
// 180.862 us; speedup vs baseline: 1.2071x; 1.0355x over previous
//
#include <hip/hip_runtime.h>
#include <math.h>

#define D_FEAT 128
#define SCAN_B 256
#define C_MAX  40
#define FIXP   33554432.0f   // 2^25 fixed-point scale for packed degree sum

#define FLAG_AGG (1ull << 32)
#define FLAG_INC (2ull << 32)

// ---------------- bf16 helpers ----------------

__device__ __forceinline__ unsigned bf16_rne(float x) {
    unsigned u = __float_as_uint(x);
    return (u + 0x7fffu + ((u >> 16) & 1u)) >> 16;
}
__device__ __forceinline__ unsigned pack2(float x, float y) {
    return bf16_rne(x) | (bf16_rne(y) << 16);
}
__device__ __forceinline__ float lo_f(unsigned g) { return __uint_as_float(g << 16); }
__device__ __forceinline__ float hi_f(unsigned g) { return __uint_as_float(g & 0xffff0000u); }

// ---------------- init: deg64 = 1.0 (self-loop) packed, count 0; scan state reset ----

__global__ void k_init(unsigned long long* __restrict__ deg64,
                       unsigned* __restrict__ ticket,
                       unsigned long long* __restrict__ chunkState,
                       int N, int nchunks) {
    int i = blockIdx.x * blockDim.x + threadIdx.x;
    if (i < N) deg64[i] = (unsigned long long)(1.0f * FIXP);
    if (i < nchunks) chunkState[i] = 0ull;
    if (i == 0) *ticket = 0u;
}

// one 64-bit atomic per edge: count in bits[40..), fixed-point val sum in bits[0..40)
__global__ void k_deg_hist(const int* __restrict__ row, const float* __restrict__ val,
                           unsigned long long* __restrict__ deg64,
                           int* __restrict__ rank, int E) {
    int e = blockIdx.x * blockDim.x + threadIdx.x;
    if (e >= E) return;
    int r = row[e];
    unsigned long long add = (1ull << 40) |
                             (unsigned long long)(val[e] * FIXP + 0.5f);
    unsigned long long old = atomicAdd(&deg64[r], add);
    rank[e] = (int)(old >> 40);
}

// ---------------- single-kernel CSR build: dinv + padded-count scan + pad fill ----
// Decoupled-lookback prefix scan over 8-padded counts; pad slots zeroed here.

__global__ __launch_bounds__(SCAN_B) void k_scan_all(const unsigned long long* __restrict__ deg64,
                                                     float* __restrict__ dinv,
                                                     int* __restrict__ rowptr,
                                                     int2* __restrict__ csr,
                                                     unsigned* __restrict__ ticket,
                                                     unsigned long long* __restrict__ chunkState,
                                                     int N, int nchunks) {
    __shared__ int s[SCAN_B];
    __shared__ int vc_s, exc_s;
    int t = threadIdx.x;
    if (t == 0) vc_s = (int)atomicAdd(ticket, 1u);
    __syncthreads();
    int vc = vc_s;
    int i = vc * SCAN_B + t;

    int cr = 0, c = 0;
    if (i < N) {
        unsigned long long p = deg64[i];
        cr = (int)(p >> 40);
        float deg = (float)(p & ((1ull << 40) - 1)) * (1.0f / FIXP);
        dinv[i] = rsqrtf(fmaxf(deg, 1e-12f));
        c = (cr + 7) & ~7;
    }
    s[t] = c;
    __syncthreads();
    for (int off = 1; off < SCAN_B; off <<= 1) {          // inclusive scan
        int add = (t >= off) ? s[t - off] : 0;
        __syncthreads();
        s[t] += add;
        __syncthreads();
    }
    int incl = s[t];
    int blockSum = s[SCAN_B - 1];

    if (t == 0) {
        int exc = 0;
        if (vc == 0) {
            atomicExch(&chunkState[0], FLAG_INC | (unsigned long long)(unsigned)blockSum);
        } else {
            atomicExch(&chunkState[vc], FLAG_AGG | (unsigned long long)(unsigned)blockSum);
            int j = vc - 1;
            int acc = 0;
            for (;;) {
                unsigned long long st;
                do { st = atomicAdd(&chunkState[j], 0ull); } while ((st >> 32) == 0);
                acc += (int)(st & 0xffffffffull);
                if (st & FLAG_INC) break;
                --j;
            }
            exc = acc;
            atomicExch(&chunkState[vc], FLAG_INC | (unsigned long long)(unsigned)(acc + blockSum));
        }
        exc_s = exc;
    }
    __syncthreads();
    int base = exc_s;

    if (i < N) {
        int rp = base + incl - c;       // exclusive
        rowptr[i] = rp;
        for (int k = cr; k < c; ++k) csr[rp + k] = make_int2(0, 0);   // zero pads
    }
    if (vc == nchunks - 1 && t == SCAN_B - 1) rowptr[N] = base + incl;  // padded total
}

// ---------------- fused scatter + convert ----------------
__global__ void k_scatter_convert(const int* __restrict__ row, const int* __restrict__ col,
                                  const float* __restrict__ val, const int* __restrict__ rank,
                                  const int* __restrict__ rowptr, int2* __restrict__ csr,
                                  const float* __restrict__ X, const float* __restrict__ dinv,
                                  unsigned* __restrict__ Xb, int E, int NV) {
    int t = blockIdx.x * blockDim.x + threadIdx.x;
    if (t < E) {
        int r = row[t];
        csr[rowptr[r] + rank[t]] = make_int2(col[t] << 8, __float_as_int(val[t]));
    } else {
        int u = t - E;
        if (u < NV) {
            float w = dinv[u >> 4];
            float4 a = ((const float4*)X)[u * 2];
            float4 b = ((const float4*)X)[u * 2 + 1];
            uint4 o;
            o.x = pack2(w * a.x, w * a.y); o.y = pack2(w * a.z, w * a.w);
            o.z = pack2(w * b.x, w * b.y); o.w = pack2(w * b.z, w * b.w);
            ((uint4*)Xb)[u] = o;
        }
    }
}

// plain scatter (f32 fallback path only)
__global__ void k_scatter(const int* __restrict__ row, const int* __restrict__ col,
                          const float* __restrict__ val, const int* __restrict__ rank,
                          const int* __restrict__ rowptr, int2* __restrict__ csr, int E) {
    int e = blockIdx.x * blockDim.x + threadIdx.x;
    if (e >= E) return;
    int r = row[e];
    csr[rowptr[r] + rank[e]] = make_int2(col[e] << 8, __float_as_int(val[e]));
}

// ---------------- SpMM row core (single row/wave, 16-deep, byte offsets) ------
// Wave = 1 row, lane i holds feature dword i (2 bf16). 1-dword/lane gathers are
// fully coalesced (256 B/instruction); 16 gathers in flight in the main block.

__device__ __forceinline__ float2 spmm_row_bf16(const int* __restrict__ rowptr,
                                                const int2* __restrict__ csr,
                                                const char* __restrict__ XbB,
                                                int rowi, int lane) {
    const unsigned lane4 = (unsigned)lane << 2;
    unsigned gs = *(const unsigned*)(XbB + ((unsigned)rowi << 8) + lane4);
    float2 a0 = make_float2(lo_f(gs), hi_f(gs));   // self term, weight 1
    float2 a1 = make_float2(0.f, 0.f), a2 = make_float2(0.f, 0.f), a3 = make_float2(0.f, 0.f);
    int e  = rowptr[rowi];
    int e1 = rowptr[rowi + 1];                     // (e1-e) % 8 == 0 by padding

    // main: 16 edges / iteration (16 outstanding gathers)
    for (; e + 16 <= e1; e += 16) {
        const int4* cp = (const int4*)(csr + e);
        int4 q0 = cp[0], q1 = cp[1], q2 = cp[2], q3 = cp[3];
        int4 q4 = cp[4], q5 = cp[5], q6 = cp[6], q7 = cp[7];
        unsigned g0 = *(const unsigned*)(XbB + (unsigned)q0.x + lane4);
        unsigned g1 = *(const unsigned*)(XbB + (unsigned)q0.z + lane4);
        unsigned g2 = *(const unsigned*)(XbB + (unsigned)q1.x + lane4);
        unsigned g3 = *(const unsigned*)(XbB + (unsigned)q1.z + lane4);
        unsigned g4 = *(const unsigned*)(XbB + (unsigned)q2.x + lane4);
        unsigned g5 = *(const unsigned*)(XbB + (unsigned)q2.z + lane4);
        unsigned g6 = *(const unsigned*)(XbB + (unsigned)q3.x + lane4);
        unsigned g7 = *(const unsigned*)(XbB + (unsigned)q3.z + lane4);
        unsigned g8 = *(const unsigned*)(XbB + (unsigned)q4.x + lane4);
        unsigned g9 = *(const unsigned*)(XbB + (unsigned)q4.z + lane4);
        unsigned ga = *(const unsigned*)(XbB + (unsigned)q5.x + lane4);
        unsigned gb = *(const unsigned*)(XbB + (unsigned)q5.z + lane4);
        unsigned gc = *(const unsigned*)(XbB + (unsigned)q6.x + lane4);
        unsigned gd = *(const unsigned*)(XbB + (unsigned)q6.z + lane4);
        unsigned ge = *(const unsigned*)(XbB + (unsigned)q7.x + lane4);
        unsigned gf = *(const unsigned*)(XbB + (unsigned)q7.z + lane4);
        float w0 = __int_as_float(q0.y), w1 = __int_as_float(q0.w);
        float w2 = __int_as_float(q1.y), w3 = __int_as_float(q1.w);
        float w4 = __int_as_float(q2.y), w5 = __int_as_float(q2.w);
        float w6 = __int_as_float(q3.y), w7 = __int_as_float(q3.w);
        float w8 = __int_as_float(q4.y), w9 = __int_as_float(q4.w);
        float wa = __int_as_float(q5.y), wb = __int_as_float(q5.w);
        float wc = __int_as_float(q6.y), wd = __int_as_float(q6.w);
        float we = __int_as_float(q7.y), wf = __int_as_float(q7.w);
        a0.x += w0 * lo_f(g0); a0.y += w0 * hi_f(g0);
        a1.x += w1 * lo_f(g1); a1.y += w1 * hi_f(g1);
        a2.x += w2 * lo_f(g2); a2.y += w2 * hi_f(g2);
        a3.x += w3 * lo_f(g3); a3.y += w3 * hi_f(g3);
        a0.x += w4 * lo_f(g4); a0.y += w4 * hi_f(g4);
        a1.x += w5 * lo_f(g5); a1.y += w5 * hi_f(g5);
        a2.x += w6 * lo_f(g6); a2.y += w6 * hi_f(g6);
        a3.x += w7 * lo_f(g7); a3.y += w7 * hi_f(g7);
        a0.x += w8 * lo_f(g8); a0.y += w8 * hi_f(g8);
        a1.x += w9 * lo_f(g9); a1.y += w9 * hi_f(g9);
        a2.x += wa * lo_f(ga); a2.y += wa * hi_f(ga);
        a3.x += wb * lo_f(gb); a3.y += wb * hi_f(gb);
        a0.x += wc * lo_f(gc); a0.y += wc * hi_f(gc);
        a1.x += wd * lo_f(gd); a1.y += wd * hi_f(gd);
        a2.x += we * lo_f(ge); a2.y += we * hi_f(ge);
        a3.x += wf * lo_f(gf); a3.y += wf * hi_f(gf);
    }
    // remainder: exactly 0 or 8 edges
    if (e < e1) {
        const int4* cp = (const int4*)(csr + e);
        int4 q0 = cp[0], q1 = cp[1], q2 = cp[2], q3 = cp[3];
        unsigned g0 = *(const unsigned*)(XbB + (unsigned)q0.x + lane4);
        unsigned g1 = *(const unsigned*)(XbB + (unsigned)q0.z + lane4);
        unsigned g2 = *(const unsigned*)(XbB + (unsigned)q1.x + lane4);
        unsigned g3 = *(const unsigned*)(XbB + (unsigned)q1.z + lane4);
        unsigned g4 = *(const unsigned*)(XbB + (unsigned)q2.x + lane4);
        unsigned g5 = *(const unsigned*)(XbB + (unsigned)q2.z + lane4);
        unsigned g6 = *(const unsigned*)(XbB + (unsigned)q3.x + lane4);
        unsigned g7 = *(const unsigned*)(XbB + (unsigned)q3.z + lane4);
        float w0 = __int_as_float(q0.y), w1 = __int_as_float(q0.w);
        float w2 = __int_as_float(q1.y), w3 = __int_as_float(q1.w);
        float w4 = __int_as_float(q2.y), w5 = __int_as_float(q2.w);
        float w6 = __int_as_float(q3.y), w7 = __int_as_float(q3.w);
        a0.x += w0 * lo_f(g0); a0.y += w0 * hi_f(g0);
        a1.x += w1 * lo_f(g1); a1.y += w1 * hi_f(g1);
        a2.x += w2 * lo_f(g2); a2.y += w2 * hi_f(g2);
        a3.x += w3 * lo_f(g3); a3.y += w3 * hi_f(g3);
        a0.x += w4 * lo_f(g4); a0.y += w4 * hi_f(g4);
        a1.x += w5 * lo_f(g5); a1.y += w5 * hi_f(g5);
        a2.x += w6 * lo_f(g6); a2.y += w6 * hi_f(g6);
        a3.x += w7 * lo_f(g7); a3.y += w7 * hi_f(g7);
    }
    float2 acc;
    acc.x = (a0.x + a1.x) + (a2.x + a3.x);
    acc.y = (a0.y + a1.y) + (a2.y + a3.y);
    return acc;
}

// ---------------- concrete SpMM kernels ----------------

__global__ __launch_bounds__(256) void k_spmm_l1(const int* __restrict__ rowptr,
                                                 const int2* __restrict__ csr,
                                                 const float* __restrict__ dinv,
                                                 const unsigned* __restrict__ Xb,
                                                 float* __restrict__ Xout,
                                                 unsigned* __restrict__ XbOut, int N) {
    int lane = threadIdx.x & 63;
    int wid  = threadIdx.x >> 6;
    int rowi = blockIdx.x * 4 + wid;
    if (rowi >= N) return;
    float2 acc = spmm_row_bf16(rowptr, csr, (const char*)Xb, rowi, lane);
    float dr = dinv[rowi];
    float2 x1 = make_float2(dr * acc.x, dr * acc.y);
    ((float2*)Xout)[(size_t)rowi * 64 + lane] = x1;
    XbOut[((unsigned)rowi << 6) | lane] = pack2(dr * x1.x, dr * x1.y);  // prescaled for layer 2
}

// round-2 head: lin staged in LDS (20 KB); proven 69 us config
__global__ __launch_bounds__(256) void k_spmm_l2_head(const int* __restrict__ rowptr,
                                                      const int2* __restrict__ csr,
                                                      const float* __restrict__ dinv,
                                                      const unsigned* __restrict__ Xb,
                                                      float* __restrict__ Xout,
                                                      const float* __restrict__ lin,
                                                      float* __restrict__ lsm,
                                                      float* __restrict__ logits,
                                                      int N, int C) {
    __shared__ float lin_s[D_FEAT * C_MAX];
    __shared__ float xs[4][D_FEAT];
    int lane = threadIdx.x & 63;
    int wid  = threadIdx.x >> 6;
    int rowi = blockIdx.x * 4 + wid;

    for (int i = threadIdx.x; i < D_FEAT * C; i += 256) lin_s[i] = lin[i];

    if (rowi < N) {
        float2 acc = spmm_row_bf16(rowptr, csr, (const char*)Xb, rowi, lane);
        float dr = dinv[rowi];
        float2 x2 = make_float2(dr * acc.x, dr * acc.y);
        ((float2*)Xout)[(size_t)rowi * 64 + lane] = x2;
        xs[wid][2 * lane]     = x2.x;
        xs[wid][2 * lane + 1] = x2.y;
    }
    __syncthreads();
    if (rowi >= N) return;

    float a = 0.0f;
    if (lane < C) {
#pragma unroll 8
        for (int d = 0; d < D_FEAT; ++d)
            a += xs[wid][d] * lin_s[d * C + lane];
    }
    float m = (lane < C) ? a : -INFINITY;
    for (int off = 32; off; off >>= 1) m = fmaxf(m, __shfl_xor(m, off));
    float ev = (lane < C) ? __expf(a - m) : 0.0f;
    float s = ev;
    for (int off = 32; off; off >>= 1) s += __shfl_xor(s, off);
    float lse = m + logf(s);
    if (lane < C) {
        logits[(size_t)rowi * C + lane] = a;
        lsm[(size_t)rowi * C + lane]    = a - lse;
    }
}

// ---------------- f32 fallback (only if workspace can't fit bf16 mirrors) ----------------

__global__ __launch_bounds__(256) void k_spmm_f32(const int* __restrict__ rowptr,
                                                  const int2* __restrict__ csr,
                                                  const float* __restrict__ dinv,
                                                  const float* __restrict__ Xin,
                                                  float* __restrict__ Xout, int N) {
    int lane = threadIdx.x & 63;
    int wid  = threadIdx.x >> 6;
    int rowi = blockIdx.x * 4 + wid;
    if (rowi >= N) return;
    const float2* Xin2 = (const float2*)Xin;
    float dr = dinv[rowi];
    float2 v0 = Xin2[(size_t)rowi * 64 + lane];
    float2 a0 = make_float2(dr * v0.x, dr * v0.y);   // self: dinv_r * X_r (pre final scale)
    float2 a1 = make_float2(0.f, 0.f);
    int e  = rowptr[rowi];
    int e1 = rowptr[rowi + 1];
    for (; e < e1; e += 2) {
        int2 q0 = csr[e], q1 = csr[e + 1];
        unsigned c0 = (unsigned)q0.x >> 8, c1 = (unsigned)q1.x >> 8;
        float w0 = __int_as_float(q0.y) * dinv[c0];
        float w1 = __int_as_float(q1.y) * dinv[c1];
        float2 g0 = Xin2[(size_t)c0 * 64 + lane];
        float2 g1 = Xin2[(size_t)c1 * 64 + lane];
        a0.x += w0 * g0.x; a0.y += w0 * g0.y;
        a1.x += w1 * g1.x; a1.y += w1 * g1.y;
    }
    float2 acc = make_float2(dr * (a0.x + a1.x), dr * (a0.y + a1.y));
    ((float2*)Xout)[(size_t)rowi * 64 + lane] = acc;
}

__global__ __launch_bounds__(256) void k_head(const float* __restrict__ X,
                                              const float* __restrict__ lin,
                                              float* __restrict__ lsm,
                                              float* __restrict__ logits,
                                              int N, int C) {
    __shared__ float xs[4][D_FEAT];
    int lane = threadIdx.x & 63;
    int wid  = threadIdx.x >> 6;
    int node = blockIdx.x * 4 + wid;
    if (node < N) {
        xs[wid][lane]      = X[(size_t)node * D_FEAT + lane];
        xs[wid][lane + 64] = X[(size_t)node * D_FEAT + 64 + lane];
    }
    __syncthreads();
    if (node >= N) return;

    float acc = 0.0f;
    if (lane < C) {
        for (int d = 0; d < D_FEAT; ++d)
            acc += xs[wid][d] * lin[d * C + lane];
    }
    float m = (lane < C) ? acc : -INFINITY;
    for (int off = 32; off; off >>= 1) m = fmaxf(m, __shfl_xor(m, off));
    float ev = (lane < C) ? __expf(acc - m) : 0.0f;
    float s = ev;
    for (int off = 32; off; off >>= 1) s += __shfl_xor(s, off);
    float lse = m + logf(s);
    if (lane < C) {
        logits[(size_t)node * C + lane] = acc;
        lsm[(size_t)node * C + lane]    = acc - lse;
    }
}

// ---------------- launch ----------------

extern "C" void kernel_launch(void* const* d_in, const int* in_sizes, int n_in,
                              void* d_out, int out_size, void* d_ws, size_t ws_size,
                              hipStream_t stream) {
    const float* features = (const float*)d_in[0];
    const int*   adj_row  = (const int*)d_in[1];
    const int*   adj_col  = (const int*)d_in[2];
    const float* adj_val  = (const float*)d_in[3];
    const float* lin      = (const float*)d_in[4];

    const int N = in_sizes[0] / D_FEAT;
    const int E = in_sizes[1];
    const int C = in_sizes[4] / D_FEAT;
    const int csrTot = E + 8 * N;   // worst-case padded edge count
    const int nchunks = (N + SCAN_B - 1) / SCAN_B;

    float* out = (float*)d_out;
    const size_t NC = (size_t)N * C;
    const size_t ND = (size_t)N * D_FEAT;
    float* lsm    = out;
    float* logits = out + NC;
    float* X1     = out + 2 * NC;
    float* X2     = out + 2 * NC + ND;

    // workspace layout (16B-aligned chunks)
    char* wp = (char*)d_ws;
    auto alloc = [&](size_t bytes) { char* p = wp; wp += (bytes + 15) & ~(size_t)15; return p; };
    unsigned long long* deg64      = (unsigned long long*)alloc((size_t)N * 8);
    float*              dinv       = (float*)alloc((size_t)N * 4);
    int*                rowptr     = (int*)alloc((size_t)(N + 1) * 4);
    unsigned*           ticket     = (unsigned*)alloc(16);
    unsigned long long* chunkState = (unsigned long long*)alloc((size_t)nchunks * 8);
    int*                rank       = (int*)alloc((size_t)E * 4);
    int2*               csr        = (int2*)alloc((size_t)csrTot * 8);
    unsigned*           Xb0        = (unsigned*)alloc((size_t)N * (D_FEAT / 2) * 4);
    unsigned*           Xb1        = (unsigned*)alloc((size_t)N * (D_FEAT / 2) * 4);

    const bool bf16_ok = ((size_t)(wp - (char*)d_ws) <= ws_size) && (C <= C_MAX);

    const int B = 256;

    k_init<<<(N + B - 1) / B, B, 0, stream>>>(deg64, ticket, chunkState, N, nchunks);
    k_deg_hist<<<(E + B - 1) / B, B, 0, stream>>>(adj_row, adj_val, deg64, rank, E);
    k_scan_all<<<nchunks, SCAN_B, 0, stream>>>(deg64, dinv, rowptr, csr,
                                               ticket, chunkState, N, nchunks);

    if (bf16_ok) {
        const int NV = N * (D_FEAT / 8);     // uint4 convert items
        k_scatter_convert<<<(E + NV + B - 1) / B, B, 0, stream>>>(adj_row, adj_col, adj_val,
                                                                  rank, rowptr, csr,
                                                                  features, dinv, Xb0, E, NV);
        int spmmBlocks = (N + 3) / 4;
        k_spmm_l1<<<spmmBlocks, 256, 0, stream>>>(rowptr, csr, dinv, Xb0, X1, Xb1, N);
        k_spmm_l2_head<<<spmmBlocks, 256, 0, stream>>>(rowptr, csr, dinv, Xb1, X2,
                                                       lin, lsm, logits, N, C);
    } else {
        k_scatter<<<(E + B - 1) / B, B, 0, stream>>>(adj_row, adj_col, adj_val, rank,
                                                     rowptr, csr, E);
        int spmmBlocks = (N + 3) / 4;
        k_spmm_f32<<<spmmBlocks, 256, 0, stream>>>(rowptr, csr, dinv, features, X1, N);
        k_spmm_f32<<<spmmBlocks, 256, 0, stream>>>(rowptr, csr, dinv, X1, X2, N);
        k_head<<<(N + 3) / 4, 256, 0, stream>>>(X2, lin, lsm, logits, N, C);
    }
}